// Round 6
// baseline (124.914 us; speedup 1.0000x reference)
//
#include <hip/hip_runtime.h>

// Problem dims (fixed by setup_inputs): feat [B,H,W,D,F] float32
#define BB 32
#define HH 128
#define WW 128
#define DD 16
#define FF 8
#define VEC_PER_ROW 32              // DD*FF floats = 32 float4 per (b,h,w) row
#define HW (HH * WW)
#define PLANE_VEC (HW * VEC_PER_ROW)      // 524288 float4 per batch plane (2^19)

// 8x-oversubscribed grid (16384 blocks vs ~2048 resident) for dynamic
// balancing of the zero-work rotation-invalid region (round-5 win, kept).
// NEW (round 6): XCD-ownership swizzle. blockIdx.x & 7 selects the batch-plane
// group AND (via round-robin dispatch) the XCD, so XCD k exclusively reads
// planes {k, k+8, k+16, k+24}. No source cache line is ever pulled into two
// XCDs' L2s -> fabric/L3 read traffic drops ~8x.
#define BLK  256
#define GRID (8 * PLANE_VEC / BLK)        // 16384

typedef float f32x4 __attribute__((ext_vector_type(4)));

// ---------------------------------------------------------------------------
// Kernel 1: build the (h,w)->source-row map. One entry per output (h,w):
//   map[h*W+w] = yi*W + xi  (source plane row index) or -1 if rotation-invalid.
// Composition (output -> input): flip2 -> roll -> rotate.
// Float math replicates the reference EXACTLY: double trig cast to f32,
// pure f32 mul/add (no FMA contraction), rintf = round-half-even (np.round).
// ---------------------------------------------------------------------------
__global__ void build_map_kernel(const int* __restrict__ rot_deg,
                                 const int* __restrict__ shift_h,
                                 const int* __restrict__ shift_w,
                                 const int* __restrict__ flip2,
                                 int* __restrict__ map) {
    int idx = blockIdx.x * blockDim.x + threadIdx.x;
    if (idx >= HW) return;
    int h = idx >> 7;
    int w = idx & (WW - 1);

    int sh = *shift_h;
    int sw = *shift_w;
    int f2 = *flip2;

    double th = (double)(*rot_deg) * (3.14159265358979323846 / 180.0);
    float c = (float)cos(th);
    float s = (float)sin(th);
    const float xc = (float)(WW - 1) * 0.5f;
    const float yc = (float)(HH - 1) * 0.5f;

    int i  = (h - sh) & (HH - 1);              // inverse roll (rows)
    int w1 = f2 ? (WW - 1 - w) : w;            // inverse flip (cols)
    int j  = (w1 - sw) & (WW - 1);             // inverse roll (cols)

    float dx = (float)j - xc;
    float dy = (float)i - yc;
    float xs = __fadd_rn(__fadd_rn(__fmul_rn(c, dx), __fmul_rn(s, dy)), xc);
    float ys = __fadd_rn(__fadd_rn(__fmul_rn(-s, dx), __fmul_rn(c, dy)), yc);
    int xi = (int)rintf(xs);
    int yi = (int)rintf(ys);
    bool valid = (xi >= 0) && (xi < WW) && (yi >= 0) && (yi < HH);
    map[idx] = valid ? (yi * WW + xi) : -1;
}

// ---------------------------------------------------------------------------
// Kernel 2: row gather.
//   b0     = blockIdx.x & 7      -> XCD id AND plane-group id (exclusive)
//   hw_blk = blockIdx.x >> 3     -> position within plane
//   thread: k = tid&31 (float4 slot in row), hw = hw_blk*8 + tid>>5
//   planes handled: b0 + 8u, u = 0..3   (4-deep MLP, loads before stores)
// Writes are output-linear within each plane (fully coalesced); reads are
// 512 B row chunks, reused within one XCD's L2 only.
// Invalid rows: zero-store, reads skipped (uniform per 32-lane row).
// ---------------------------------------------------------------------------
__global__ void __launch_bounds__(BLK)
gather_kernel(const f32x4* __restrict__ src,
              f32x4* __restrict__ dst,
              const int* __restrict__ map,
              const int* __restrict__ flip3) {
    const int bid = blockIdx.x;
    const int b0  = bid & 7;                                // XCD / plane group
    const int t   = ((bid >> 3) << 8) | (int)threadIdx.x;   // [0, PLANE_VEC)
    const int k   = t & (VEC_PER_ROW - 1);
    const int hw  = t >> 5;                                 // [0, HW)
    const int m   = map[hw];

    const size_t slot = ((size_t)hw << 5) + (size_t)k;      // float4 idx in plane
    f32x4* __restrict__ d = dst + ((size_t)b0 << 19) + slot;

    if (m >= 0) {
        const int f3 = *flip3;
        // flip3 reverses D (16 slots of 2 float4) within the row
        const int kk = f3 ? ((((DD - 1) - (k >> 1)) << 1) | (k & 1)) : k;
        const f32x4* __restrict__ s =
            src + ((size_t)b0 << 19) + ((size_t)m << 5) + (size_t)kk;
        f32x4 v0 = s[(size_t)(8 * 0) * PLANE_VEC];
        f32x4 v1 = s[(size_t)(8 * 1) * PLANE_VEC];
        f32x4 v2 = s[(size_t)(8 * 2) * PLANE_VEC];
        f32x4 v3 = s[(size_t)(8 * 3) * PLANE_VEC];
        d[(size_t)(8 * 0) * PLANE_VEC] = v0;
        d[(size_t)(8 * 1) * PLANE_VEC] = v1;
        d[(size_t)(8 * 2) * PLANE_VEC] = v2;
        d[(size_t)(8 * 3) * PLANE_VEC] = v3;
    } else {
        const f32x4 z = (f32x4){0.f, 0.f, 0.f, 0.f};
        d[(size_t)(8 * 0) * PLANE_VEC] = z;
        d[(size_t)(8 * 1) * PLANE_VEC] = z;
        d[(size_t)(8 * 2) * PLANE_VEC] = z;
        d[(size_t)(8 * 3) * PLANE_VEC] = z;
    }
}

extern "C" void kernel_launch(void* const* d_in, const int* in_sizes, int n_in,
                              void* d_out, int out_size, void* d_ws, size_t ws_size,
                              hipStream_t stream) {
    const float* feat = (const float*)d_in[0];
    const int* rot    = (const int*)d_in[1];
    const int* sh     = (const int*)d_in[2];
    const int* sw     = (const int*)d_in[3];
    const int* f2     = (const int*)d_in[4];
    const int* f3     = (const int*)d_in[5];
    float* out = (float*)d_out;

    int* map = (int*)d_ws;   // 64 KB; ws proven sufficient
    build_map_kernel<<<(HW + 255) / 256, 256, 0, stream>>>(rot, sh, sw, f2, map);
    gather_kernel<<<GRID, BLK, 0, stream>>>((const f32x4*)feat, (f32x4*)out, map, f3);
}

// Round 7
// 107.701 us; speedup vs baseline: 1.1598x; 1.1598x over previous
//
#include <hip/hip_runtime.h>

// Problem dims (fixed by setup_inputs): feat [B,H,W,D,F] float32
#define BB 32
#define HH 128
#define WW 128
#define DD 16
#define FF 8
#define VEC_PER_ROW 32              // DD*FF floats = 32 float4 per (b,h,w) row
#define HW (HH * WW)
#define PLANE_VEC (HW * VEC_PER_ROW)      // 524288 float4 per batch plane (2^19)

// R5 structure kept: 8x-oversubscribed grid (16384 blocks vs ~2048 resident)
// for dynamic balancing of zero-work rotation-invalid rows; 4 planes per
// thread (4-deep MLP). R7 change: h-FAST output traversal. At rot=80deg,
// d(src_addr)/dh ~ cos80*512B + sin80*64KB_wrap ~ +504B -> consecutive waves
// read a nearly-sequential source stream (reads stall waves; writes are
// posted and aggregate in L2, so scatter is cheaper on the write side).
#define BLK  256
#define GRID (8 * PLANE_VEC / BLK)        // 16384

typedef float f32x4 __attribute__((ext_vector_type(4)));

// ---------------------------------------------------------------------------
// Kernel 1: build the (h,w)->source-row map. One entry per output (h,w):
//   map[h*W+w] = yi*W + xi  (source plane row index) or -1 if rotation-invalid.
// Composition (output -> input): flip2 -> roll -> rotate.
// Float math replicates the reference EXACTLY: double trig cast to f32,
// pure f32 mul/add (no FMA contraction), rintf = round-half-even (np.round).
// ---------------------------------------------------------------------------
__global__ void build_map_kernel(const int* __restrict__ rot_deg,
                                 const int* __restrict__ shift_h,
                                 const int* __restrict__ shift_w,
                                 const int* __restrict__ flip2,
                                 int* __restrict__ map) {
    int idx = blockIdx.x * blockDim.x + threadIdx.x;
    if (idx >= HW) return;
    int h = idx >> 7;
    int w = idx & (WW - 1);

    int sh = *shift_h;
    int sw = *shift_w;
    int f2 = *flip2;

    double th = (double)(*rot_deg) * (3.14159265358979323846 / 180.0);
    float c = (float)cos(th);
    float s = (float)sin(th);
    const float xc = (float)(WW - 1) * 0.5f;
    const float yc = (float)(HH - 1) * 0.5f;

    int i  = (h - sh) & (HH - 1);              // inverse roll (rows)
    int w1 = f2 ? (WW - 1 - w) : w;            // inverse flip (cols)
    int j  = (w1 - sw) & (WW - 1);             // inverse roll (cols)

    float dx = (float)j - xc;
    float dy = (float)i - yc;
    float xs = __fadd_rn(__fadd_rn(__fmul_rn(c, dx), __fmul_rn(s, dy)), xc);
    float ys = __fadd_rn(__fadd_rn(__fmul_rn(-s, dx), __fmul_rn(c, dy)), yc);
    int xi = (int)rintf(xs);
    int yi = (int)rintf(ys);
    bool valid = (xi >= 0) && (xi < WW) && (yi >= 0) && (yi < HH);
    map[idx] = valid ? (yi * WW + xi) : -1;
}

// ---------------------------------------------------------------------------
// Kernel 2: row gather, h-FAST traversal + 8x oversubscription + 4-plane MLP.
//   t in [0, 8*PLANE_VEC):
//     k  = t & 31          float4 slot within the 512B row
//     h  = (t >> 5) & 127  FAST spatial dim  -> near-sequential source reads
//     w  = (t >> 12) & 127
//     b0 = t >> 19         plane group; planes b0 + 8u, u = 0..3
// Writes: each 32-thread group writes one full 512B output row (coalesced,
// full lines); consecutive groups 64KB apart (posted, L2-aggregated).
// Invalid rows: zero-store, reads skipped (uniform per 32-lane group).
// ---------------------------------------------------------------------------
__global__ void __launch_bounds__(BLK)
gather_kernel(const f32x4* __restrict__ src,
              f32x4* __restrict__ dst,
              const int* __restrict__ map,
              const int* __restrict__ flip3) {
    const int t  = blockIdx.x * BLK + (int)threadIdx.x;   // [0, 8*PLANE_VEC)
    const int k  = t & (VEC_PER_ROW - 1);
    const int h  = (t >> 5) & (HH - 1);
    const int w  = (t >> 12) & (WW - 1);
    const int b0 = t >> 19;                               // [0, 8)
    const int hw = (h << 7) | w;
    const int m  = map[hw];

    const size_t slot = ((size_t)hw << 5) + (size_t)k;    // float4 idx in plane
    f32x4* __restrict__ d = dst + ((size_t)b0 << 19) + slot;

    if (m >= 0) {
        const int f3 = *flip3;
        // flip3 reverses D (16 slots of 2 float4) within the row
        const int kk = f3 ? ((((DD - 1) - (k >> 1)) << 1) | (k & 1)) : k;
        const f32x4* __restrict__ s =
            src + ((size_t)b0 << 19) + ((size_t)m << 5) + (size_t)kk;
        f32x4 v0 = s[(size_t)(8 * 0) * PLANE_VEC];
        f32x4 v1 = s[(size_t)(8 * 1) * PLANE_VEC];
        f32x4 v2 = s[(size_t)(8 * 2) * PLANE_VEC];
        f32x4 v3 = s[(size_t)(8 * 3) * PLANE_VEC];
        d[(size_t)(8 * 0) * PLANE_VEC] = v0;
        d[(size_t)(8 * 1) * PLANE_VEC] = v1;
        d[(size_t)(8 * 2) * PLANE_VEC] = v2;
        d[(size_t)(8 * 3) * PLANE_VEC] = v3;
    } else {
        const f32x4 z = (f32x4){0.f, 0.f, 0.f, 0.f};
        d[(size_t)(8 * 0) * PLANE_VEC] = z;
        d[(size_t)(8 * 1) * PLANE_VEC] = z;
        d[(size_t)(8 * 2) * PLANE_VEC] = z;
        d[(size_t)(8 * 3) * PLANE_VEC] = z;
    }
}

extern "C" void kernel_launch(void* const* d_in, const int* in_sizes, int n_in,
                              void* d_out, int out_size, void* d_ws, size_t ws_size,
                              hipStream_t stream) {
    const float* feat = (const float*)d_in[0];
    const int* rot    = (const int*)d_in[1];
    const int* sh     = (const int*)d_in[2];
    const int* sw     = (const int*)d_in[3];
    const int* f2     = (const int*)d_in[4];
    const int* f3     = (const int*)d_in[5];
    float* out = (float*)d_out;

    int* map = (int*)d_ws;   // 64 KB; ws proven sufficient
    build_map_kernel<<<(HW + 255) / 256, 256, 0, stream>>>(rot, sh, sw, f2, map);
    gather_kernel<<<GRID, BLK, 0, stream>>>((const f32x4*)feat, (f32x4*)out, map, f3);
}

// Round 8
// 81.617 us; speedup vs baseline: 1.5305x; 1.3196x over previous
//
#include <hip/hip_runtime.h>

// Problem dims (fixed by setup_inputs): feat [B,H,W,D,F] float32
#define BB 32
#define HH 128
#define WW 128
#define DD 16
#define FF 8
#define VEC_PER_ROW 32              // DD*FF floats = 32 float4 per (b,h,w) row
#define HW (HH * WW)
#define PLANE_VEC (HW * VEC_PER_ROW)      // 524288 float4 per batch plane (2^19)

// Structure = R7 (best, 107.7us): 8x-oversubscribed grid, h-fast traversal,
// 4 planes per thread (4-deep MLP), zero-skip on invalid rows.
// R8 change: NONTEMPORAL STORES ONLY. Output is never re-read; write-allocate
// in L2 (262MB stream through 32MB L2) evicts the source lines whose reuse
// keeps reads fast. NT stores keep L2 for the read stream. (R2's regression
// was NT on LOADS too, which killed read caching.)
#define BLK  256
#define GRID (8 * PLANE_VEC / BLK)        // 16384

typedef float f32x4 __attribute__((ext_vector_type(4)));

// ---------------------------------------------------------------------------
// Kernel 1: build the (h,w)->source-row map. One entry per output (h,w):
//   map[h*W+w] = yi*W + xi  (source plane row index) or -1 if rotation-invalid.
// Composition (output -> input): flip2 -> roll -> rotate.
// Float math replicates the reference EXACTLY: double trig cast to f32,
// pure f32 mul/add (no FMA contraction), rintf = round-half-even (np.round).
// ---------------------------------------------------------------------------
__global__ void build_map_kernel(const int* __restrict__ rot_deg,
                                 const int* __restrict__ shift_h,
                                 const int* __restrict__ shift_w,
                                 const int* __restrict__ flip2,
                                 int* __restrict__ map) {
    int idx = blockIdx.x * blockDim.x + threadIdx.x;
    if (idx >= HW) return;
    int h = idx >> 7;
    int w = idx & (WW - 1);

    int sh = *shift_h;
    int sw = *shift_w;
    int f2 = *flip2;

    double th = (double)(*rot_deg) * (3.14159265358979323846 / 180.0);
    float c = (float)cos(th);
    float s = (float)sin(th);
    const float xc = (float)(WW - 1) * 0.5f;
    const float yc = (float)(HH - 1) * 0.5f;

    int i  = (h - sh) & (HH - 1);              // inverse roll (rows)
    int w1 = f2 ? (WW - 1 - w) : w;            // inverse flip (cols)
    int j  = (w1 - sw) & (WW - 1);             // inverse roll (cols)

    float dx = (float)j - xc;
    float dy = (float)i - yc;
    float xs = __fadd_rn(__fadd_rn(__fmul_rn(c, dx), __fmul_rn(s, dy)), xc);
    float ys = __fadd_rn(__fadd_rn(__fmul_rn(-s, dx), __fmul_rn(c, dy)), yc);
    int xi = (int)rintf(xs);
    int yi = (int)rintf(ys);
    bool valid = (xi >= 0) && (xi < WW) && (yi >= 0) && (yi < HH);
    map[idx] = valid ? (yi * WW + xi) : -1;
}

// ---------------------------------------------------------------------------
// Kernel 2: row gather, h-FAST traversal + 8x oversubscription + 4-plane MLP
// + NT stores.
//   t in [0, 8*PLANE_VEC):
//     k  = t & 31          float4 slot within the 512B row
//     h  = (t >> 5) & 127  FAST spatial dim  -> near-sequential source reads
//     w  = (t >> 12) & 127
//     b0 = t >> 19         plane group; planes b0 + 8u, u = 0..3
// ---------------------------------------------------------------------------
__global__ void __launch_bounds__(BLK)
gather_kernel(const f32x4* __restrict__ src,
              f32x4* __restrict__ dst,
              const int* __restrict__ map,
              const int* __restrict__ flip3) {
    const int t  = blockIdx.x * BLK + (int)threadIdx.x;   // [0, 8*PLANE_VEC)
    const int k  = t & (VEC_PER_ROW - 1);
    const int h  = (t >> 5) & (HH - 1);
    const int w  = (t >> 12) & (WW - 1);
    const int b0 = t >> 19;                               // [0, 8)
    const int hw = (h << 7) | w;
    const int m  = map[hw];

    const size_t slot = ((size_t)hw << 5) + (size_t)k;    // float4 idx in plane
    f32x4* __restrict__ d = dst + ((size_t)b0 << 19) + slot;

    if (m >= 0) {
        const int f3 = *flip3;
        // flip3 reverses D (16 slots of 2 float4) within the row
        const int kk = f3 ? ((((DD - 1) - (k >> 1)) << 1) | (k & 1)) : k;
        const f32x4* __restrict__ s =
            src + ((size_t)b0 << 19) + ((size_t)m << 5) + (size_t)kk;
        f32x4 v0 = s[(size_t)(8 * 0) * PLANE_VEC];   // loads: PLAIN (cache!)
        f32x4 v1 = s[(size_t)(8 * 1) * PLANE_VEC];
        f32x4 v2 = s[(size_t)(8 * 2) * PLANE_VEC];
        f32x4 v3 = s[(size_t)(8 * 3) * PLANE_VEC];
        __builtin_nontemporal_store(v0, d + (size_t)(8 * 0) * PLANE_VEC);
        __builtin_nontemporal_store(v1, d + (size_t)(8 * 1) * PLANE_VEC);
        __builtin_nontemporal_store(v2, d + (size_t)(8 * 2) * PLANE_VEC);
        __builtin_nontemporal_store(v3, d + (size_t)(8 * 3) * PLANE_VEC);
    } else {
        const f32x4 z = (f32x4){0.f, 0.f, 0.f, 0.f};
        __builtin_nontemporal_store(z, d + (size_t)(8 * 0) * PLANE_VEC);
        __builtin_nontemporal_store(z, d + (size_t)(8 * 1) * PLANE_VEC);
        __builtin_nontemporal_store(z, d + (size_t)(8 * 2) * PLANE_VEC);
        __builtin_nontemporal_store(z, d + (size_t)(8 * 3) * PLANE_VEC);
    }
}

extern "C" void kernel_launch(void* const* d_in, const int* in_sizes, int n_in,
                              void* d_out, int out_size, void* d_ws, size_t ws_size,
                              hipStream_t stream) {
    const float* feat = (const float*)d_in[0];
    const int* rot    = (const int*)d_in[1];
    const int* sh     = (const int*)d_in[2];
    const int* sw     = (const int*)d_in[3];
    const int* f2     = (const int*)d_in[4];
    const int* f3     = (const int*)d_in[5];
    float* out = (float*)d_out;

    int* map = (int*)d_ws;   // 64 KB; ws proven sufficient
    build_map_kernel<<<(HW + 255) / 256, 256, 0, stream>>>(rot, sh, sw, f2, map);
    gather_kernel<<<GRID, BLK, 0, stream>>>((const f32x4*)feat, (f32x4*)out, map, f3);
}